// Round 6
// baseline (75.351 us; speedup 1.0000x reference)
//
#include <hip/hip_runtime.h>
#include <cmath>

#define MATSZ 262144                 // 2048 * 128
#define QKV_OFF 0                    // qkv[3][64][512][8]
#define AOUT_OFF (3 * MATSZ)         // aout2[64][512][8] (head-major, per-bh)
#define CNT_OFF (4 * MATSZ)          // int cnt[256] (one per 8-row out tile)

// ---------------- k_qkvq: QKV projection + quantum closed form ---------------
// thread = (col e, K-half); W row fragment in regs; x rows broadcast from LDS;
// K-halves combined via LDS partials. grid (256,3) = 768 blocks = 3/CU.
// Block (0,0) also zeroes the 256 finish-counters for the next dispatch.
__global__ __launch_bounds__(256, 3) void k_qkvq(
    const float* __restrict__ x, const float* __restrict__ Wq,
    const float* __restrict__ Wk, const float* __restrict__ Wv,
    const float* __restrict__ qp, float* __restrict__ ws) {
  __shared__ float xs[8][128];     // 4 KB
  __shared__ float th[2][8][128];  // 8 KB partial sums per K-half
  const int t = threadIdx.x;
  const int tile = blockIdx.x;  // 0..255 (8 rows each)
  const int m = blockIdx.y;     // 0..2
  if (blockIdx.x == 0 && blockIdx.y == 0) {
    ((int*)(ws + CNT_OFF))[t] = 0;  // reset finish counters (256 ints)
  }
  const float* W = (m == 0) ? Wq : (m == 1) ? Wk : Wv;
  {  // stage x tile: 8*32 = 256 float4, one per thread
    ((float4*)&xs[0][0])[t] = ((const float4*)(x + (size_t)tile * 1024))[t];
  }
  const int e = t & 127, half = t >> 7;
  float4 w[16];
  {
    const float4* wr = (const float4*)W + (size_t)e * 32 + half * 16;
#pragma unroll
    for (int i = 0; i < 16; ++i) w[i] = wr[i];  // row fragment, 64 VGPR
  }
  __syncthreads();
  const float4* xs4 = (const float4*)&xs[0][0];
#pragma unroll
  for (int r = 0; r < 8; ++r) {
    float a = 0.f;
    const float4* xr = xs4 + r * 32 + half * 16;
#pragma unroll
    for (int i = 0; i < 16; ++i) {
      float4 xv = xr[i];  // LDS broadcast (wave-uniform addr)
      a = fmaf(xv.x, w[i].x, a);
      a = fmaf(xv.y, w[i].y, a);
      a = fmaf(xv.z, w[i].z, a);
      a = fmaf(xv.w, w[i].w, a);
    }
    th[half][r][e] = a;  // lanes e-consecutive: conflict-free
  }
  __syncthreads();
  // quantum tail: thread = (row rg, half-head cg); cols 4cg..4cg+3.
  const int cg = t & 31, rg = t >> 5;
  const float4* th4 = (const float4*)&th[0][0][0];
  float4 s0 = th4[rg * 32 + cg];
  float4 s1 = th4[256 + rg * 32 + cg];
  float4 a4 = make_float4(s0.x + s1.x, s0.y + s1.y, s0.z + s1.z, s0.w + s1.w);
  const int j0 = (cg & 1) * 4;
  float4 qs;
  qs.x = qp[j0 + 0] + qp[8 + j0 + 0];
  qs.y = qp[j0 + 1] + qp[8 + j0 + 1];
  qs.z = qp[j0 + 2] + qp[8 + j0 + 2];
  qs.w = qp[j0 + 3] + qp[8 + j0 + 3];
  float4 c;
  c.x = __cosf(a4.x + qs.x);
  c.y = __cosf(a4.y + qs.y);
  c.z = __cosf(a4.z + qs.z);
  c.w = __cosf(a4.w + qs.w);
  float4 u;  // local prefix: (c0, c1, c0c2, c1c3) in this half's numbering
  u.x = c.x; u.y = c.y; u.z = c.x * c.z; u.w = c.y * c.w;
  float gz = __shfl_xor(u.z, 1);  // even lane's (c0*c2) -> odd lane
  float gw = __shfl_xor(u.w, 1);  // even lane's (c1*c3) -> odd lane
  const bool hi = (cg & 1) != 0;
  float mz = hi ? gz : 1.f, mw = hi ? gw : 1.f;
  float4 o;
  o.x = u.x * mz; o.y = u.y * mw; o.z = u.z * mz; o.w = u.w * mw;
  const int h = cg >> 1;
  int row = tile * 8 + rg;
  int b = row >> 9, s = row & 511;
  float* dst = ws + QKV_OFF + (size_t)m * MATSZ +
               ((size_t)((b << 4) + h) * 512 + s) * 8 + (hi ? 4 : 0);
  *(float4*)dst = o;
}

// ---------------- k_attn_out: attention + fused output projection ------------
// grid (8,64): (64-row q-tile, bh). Attention exactly as before; then the block
// that completes the 16th head of an 8-row tile does that tile's out-proj.
__global__ __launch_bounds__(256, 4) void k_attn_out(
    float* __restrict__ ws, const float* __restrict__ Wo,
    float* __restrict__ out) {
  __shared__ float4 smv[2048];  // 32 KB: K/V during attn; at/th during outproj
  __shared__ int finmask;
  float4* kslo = smv;
  float4* kshi = smv + 512;
  float4* vslo = smv + 1024;
  float4* vshi = smv + 1536;
  const int qt = blockIdx.x;  // 0..7
  const int bh = blockIdx.y;  // 0..63
  const int b = bh >> 4;
  const float* qkv = ws + QKV_OFF;
  const float* Qg = qkv + (size_t)bh * 4096;
  const float4* Kg = (const float4*)(qkv + MATSZ + (size_t)bh * 4096);
  const float4* Vg = (const float4*)(qkv + 2 * (size_t)MATSZ + (size_t)bh * 4096);
  const int t = threadIdx.x;
  if (t == 0) finmask = 0;
  for (int k = t; k < 512; k += 256) {
    kslo[k] = Kg[2 * k]; kshi[k] = Kg[2 * k + 1];
    vslo[k] = Vg[2 * k]; vshi[k] = Vg[2 * k + 1];
  }
  __syncthreads();
  const int qslot = t >> 4, ko = t & 15;
  const int row0 = qt * 64 + qslot * 4;  // local s of first of 4 q rows
  const float scale = 0.35355339059327373f;  // 1/sqrt(8)
  float4 qa[4], qb[4];
#pragma unroll
  for (int r = 0; r < 4; ++r) {
    qa[r] = ((const float4*)(Qg + (size_t)(row0 + r) * 8))[0];
    qb[r] = ((const float4*)(Qg + (size_t)(row0 + r) * 8))[1];
    qa[r].x *= scale; qa[r].y *= scale; qa[r].z *= scale; qa[r].w *= scale;
    qb[r].x *= scale; qb[r].y *= scale; qb[r].z *= scale; qb[r].w *= scale;
  }
  float l[4] = {0.f, 0.f, 0.f, 0.f};
  float a[4][8];
#pragma unroll
  for (int r = 0; r < 4; ++r)
#pragma unroll
    for (int j = 0; j < 8; ++j) a[r][j] = 0.f;
#pragma unroll 2
  for (int i = 0; i < 32; ++i) {
    int k = i * 16 + ko;  // 16 distinct addrs x 4-way broadcast: conflict-free
    float4 kx = kslo[k], ky = kshi[k];
    float4 vx = vslo[k], vy = vshi[k];
#pragma unroll
    for (int r = 0; r < 4; ++r) {
      float s = qa[r].x * kx.x + qa[r].y * kx.y + qa[r].z * kx.z + qa[r].w * kx.w +
                qb[r].x * ky.x + qb[r].y * ky.y + qb[r].z * ky.z + qb[r].w * ky.w;
      float p = __expf(s);  // |s| <= 2.83: no max subtraction needed
      l[r] += p;
      a[r][0] = fmaf(p, vx.x, a[r][0]);
      a[r][1] = fmaf(p, vx.y, a[r][1]);
      a[r][2] = fmaf(p, vx.z, a[r][2]);
      a[r][3] = fmaf(p, vx.w, a[r][3]);
      a[r][4] = fmaf(p, vy.x, a[r][4]);
      a[r][5] = fmaf(p, vy.y, a[r][5]);
      a[r][6] = fmaf(p, vy.z, a[r][6]);
      a[r][7] = fmaf(p, vy.w, a[r][7]);
    }
  }
#pragma unroll
  for (int mm = 1; mm <= 8; mm <<= 1) {  // reduce over 16 k-parts (in-wave)
#pragma unroll
    for (int r = 0; r < 4; ++r) {
      l[r] += __shfl_xor(l[r], mm);
#pragma unroll
      for (int j = 0; j < 8; ++j) a[r][j] += __shfl_xor(a[r][j], mm);
    }
  }
  if (ko == 0) {  // write head-major aout2[bh][s][8]: block-contiguous 2 KB
    float* aout2 = ws + AOUT_OFF + (size_t)bh * 4096;
#pragma unroll
    for (int r = 0; r < 4; ++r) {
      float inv = 1.f / l[r];
      float* d = aout2 + (size_t)(row0 + r) * 8;
      ((float4*)d)[0] = make_float4(a[r][0] * inv, a[r][1] * inv,
                                    a[r][2] * inv, a[r][3] * inv);
      ((float4*)d)[1] = make_float4(a[r][4] * inv, a[r][5] * inv,
                                    a[r][6] * inv, a[r][7] * inv);
    }
  }
  __syncthreads();     // drains vmcnt: all aout2 stores of this block issued
  int* cnt = (int*)(ws + CNT_OFF);
  if (t < 8) {
    __threadfence();   // release: write back L2 so other XCDs see aout2
    int old = atomicAdd(&cnt[b * 64 + qt * 8 + t], 1);
    if (old == 15) atomicOr(&finmask, 1 << t);
  }
  __syncthreads();
  int fm = finmask;    // uniform across block
  if (fm == 0) return;
  __threadfence();     // acquire: invalidate caches before reading aout2
  float* at = (float*)smv;          // at[8][128]  (4 KB)
  float* th = (float*)smv + 1024;   // th[2][8][128] (8 KB)
  const float* aoutb = ws + AOUT_OFF;
  while (fm) {
    int i = __ffs(fm) - 1;
    fm &= fm - 1;
    const int s0 = qt * 64 + i * 8;  // local row base of this out tile
    __syncthreads();                 // protect LDS reuse across iterations
    if (t < 128) {                   // stage at[r][h*8..]: all heads, 8 rows
      int h = t >> 3, r = t & 7;
      const float4* src =
          (const float4*)(aoutb + ((size_t)(b * 16 + h) * 512 + s0 + r) * 8);
      float4* dst = (float4*)(at + r * 128 + h * 8);
      dst[0] = src[0];
      dst[1] = src[1];
    }
    __syncthreads();
    const int e = t & 127, half = t >> 7;
    const float4* wr = (const float4*)Wo + (size_t)e * 32 + half * 16;
    const float4* at4 = (const float4*)at;
#pragma unroll
    for (int r = 0; r < 8; ++r) {
      float acc = 0.f;
      const float4* ar = at4 + r * 32 + half * 16;
#pragma unroll
      for (int ii = 0; ii < 16; ++ii) {
        float4 av = ar[ii];  // LDS broadcast
        float4 wv = wr[ii];
        acc = fmaf(av.x, wv.x, acc);
        acc = fmaf(av.y, wv.y, acc);
        acc = fmaf(av.z, wv.z, acc);
        acc = fmaf(av.w, wv.w, acc);
      }
      th[(half * 8 + r) * 128 + e] = acc;
    }
    __syncthreads();
    const int cg = t & 31, rg = t >> 5;
    const float4* th4 = (const float4*)th;
    float4 p0 = th4[rg * 32 + cg];
    float4 p1 = th4[256 + rg * 32 + cg];
    float4 o = make_float4(p0.x + p1.x, p0.y + p1.y, p0.z + p1.z, p0.w + p1.w);
    ((float4*)(out + (size_t)(b * 512 + s0 + rg) * 128))[cg] = o;
  }
}

extern "C" void kernel_launch(void* const* d_in, const int* in_sizes, int n_in,
                              void* d_out, int out_size, void* d_ws, size_t ws_size,
                              hipStream_t stream) {
  const float* x  = (const float*)d_in[0];
  const float* Wq = (const float*)d_in[1];
  const float* Wk = (const float*)d_in[2];
  const float* Wv = (const float*)d_in[3];
  const float* Wo = (const float*)d_in[4];
  const float* qp = (const float*)d_in[5];
  float* out = (float*)d_out;
  float* ws = (float*)d_ws;

  hipLaunchKernelGGL(k_qkvq, dim3(256, 3), dim3(256), 0, stream,
                     x, Wq, Wk, Wv, qp, ws);
  hipLaunchKernelGGL(k_attn_out, dim3(8, 64), dim3(256), 0, stream,
                     ws, Wo, out);
}

// Round 7
// 41.848 us; speedup vs baseline: 1.8006x; 1.8006x over previous
//
#include <hip/hip_runtime.h>
#include <cmath>

#define MATSZ 262144                 // 2048 * 128
#define QKV_OFF 0                    // qkv[3][64][512][8]
#define AOUT_OFF (3 * MATSZ)         // aout[2048][128]

// ---------------- k_qkvq: QKV projection + quantum closed form ---------------
// thread = (col e, K-half); W row fragment in regs (issued BEFORE staging
// barrier so L2 latency hides under it); x rows broadcast from LDS; K-halves
// combined via LDS partials. grid (256,3) = 768 blocks = 3/CU.
__global__ __launch_bounds__(256, 3) void k_qkvq(
    const float* __restrict__ x, const float* __restrict__ Wq,
    const float* __restrict__ Wk, const float* __restrict__ Wv,
    const float* __restrict__ qp, float* __restrict__ ws) {
  __shared__ float xs[8][128];     // 4 KB
  __shared__ float th[2][8][128];  // 8 KB partial sums per K-half
  const int t = threadIdx.x;
  const int tile = blockIdx.x;  // 0..255 (8 rows each)
  const int m = blockIdx.y;     // 0..2
  const float* W = (m == 0) ? Wq : (m == 1) ? Wk : Wv;
  const int e = t & 127, half = t >> 7;
  // issue W fragment loads first: 16 independent dwordx4, L2-resident
  float4 w[16];
  {
    const float4* wr = (const float4*)W + (size_t)e * 32 + half * 16;
#pragma unroll
    for (int i = 0; i < 16; ++i) w[i] = wr[i];
  }
  // stage x tile while W loads are in flight
  ((float4*)&xs[0][0])[t] = ((const float4*)(x + (size_t)tile * 1024))[t];
  __syncthreads();
  const float4* xs4 = (const float4*)&xs[0][0];
#pragma unroll
  for (int r = 0; r < 8; ++r) {
    float a = 0.f;
    const float4* xr = xs4 + r * 32 + half * 16;
#pragma unroll
    for (int i = 0; i < 16; ++i) {
      float4 xv = xr[i];  // LDS broadcast (wave-uniform addr)
      a = fmaf(xv.x, w[i].x, a);
      a = fmaf(xv.y, w[i].y, a);
      a = fmaf(xv.z, w[i].z, a);
      a = fmaf(xv.w, w[i].w, a);
    }
    th[half][r][e] = a;  // lanes e-consecutive: conflict-free
  }
  __syncthreads();
  // quantum tail: thread = (row rg, half-head cg); cols 4cg..4cg+3.
  const int cg = t & 31, rg = t >> 5;
  const float4* th4 = (const float4*)&th[0][0][0];
  float4 s0 = th4[rg * 32 + cg];
  float4 s1 = th4[256 + rg * 32 + cg];
  float4 a4 = make_float4(s0.x + s1.x, s0.y + s1.y, s0.z + s1.z, s0.w + s1.w);
  const int j0 = (cg & 1) * 4;
  float4 qs;
  qs.x = qp[j0 + 0] + qp[8 + j0 + 0];
  qs.y = qp[j0 + 1] + qp[8 + j0 + 1];
  qs.z = qp[j0 + 2] + qp[8 + j0 + 2];
  qs.w = qp[j0 + 3] + qp[8 + j0 + 3];
  float4 c;
  c.x = __cosf(a4.x + qs.x);
  c.y = __cosf(a4.y + qs.y);
  c.z = __cosf(a4.z + qs.z);
  c.w = __cosf(a4.w + qs.w);
  float4 u;  // local prefix: (c0, c1, c0c2, c1c3) in this half's numbering
  u.x = c.x; u.y = c.y; u.z = c.x * c.z; u.w = c.y * c.w;
  float gz = __shfl_xor(u.z, 1);  // even lane's (c0*c2) -> odd lane
  float gw = __shfl_xor(u.w, 1);  // even lane's (c1*c3) -> odd lane
  const bool hi = (cg & 1) != 0;
  float mz = hi ? gz : 1.f, mw = hi ? gw : 1.f;
  float4 o;
  o.x = u.x * mz; o.y = u.y * mw; o.z = u.z * mz; o.w = u.w * mw;
  const int h = cg >> 1;
  int row = tile * 8 + rg;
  int b = row >> 9, s = row & 511;
  float* dst = ws + QKV_OFF + (size_t)m * MATSZ +
               ((size_t)((b << 4) + h) * 512 + s) * 8 + (hi ? 4 : 0);
  *(float4*)dst = o;
}

// ---------------- k_attn: attention per (bh, 32-row q-tile) ------------------
// grid (16,64) = 1024 blocks = 4/CU (LDS 4x32KB = 128 <= 160 KB).
// 256 thr = 16 qslots (2 rows each) x 16 k-parts. K/V rows as lo/hi float4
// arrays; 16 distinct addrs x 4-way broadcast per wave access = conflict-free.
// Q prescaled by log2(e)/sqrt(8) so softmax exp is a single v_exp_f32 (exp2).
__global__ __launch_bounds__(256, 4) void k_attn(
    float* __restrict__ ws) {
  __shared__ float4 kslo[512], kshi[512], vslo[512], vshi[512];
  const int qt = blockIdx.x;  // 0..15
  const int bh = blockIdx.y;  // 0..63
  const float* qkv = ws + QKV_OFF;
  const float* Qg = qkv + (size_t)bh * 4096;
  const float4* Kg = (const float4*)(qkv + MATSZ + (size_t)bh * 4096);
  const float4* Vg = (const float4*)(qkv + 2 * (size_t)MATSZ + (size_t)bh * 4096);
  const int t = threadIdx.x;
  for (int k = t; k < 512; k += 256) {
    kslo[k] = Kg[2 * k]; kshi[k] = Kg[2 * k + 1];
    vslo[k] = Vg[2 * k]; vshi[k] = Vg[2 * k + 1];
  }
  __syncthreads();
  const int qslot = t >> 4, ko = t & 15;
  const int row0 = qt * 32 + qslot * 2;
  const float scale = 0.51013389376f;  // log2(e)/sqrt(8)
  float4 qa[2], qb[2];
#pragma unroll
  for (int r = 0; r < 2; ++r) {
    qa[r] = ((const float4*)(Qg + (size_t)(row0 + r) * 8))[0];
    qb[r] = ((const float4*)(Qg + (size_t)(row0 + r) * 8))[1];
    qa[r].x *= scale; qa[r].y *= scale; qa[r].z *= scale; qa[r].w *= scale;
    qb[r].x *= scale; qb[r].y *= scale; qb[r].z *= scale; qb[r].w *= scale;
  }
  float l[2] = {0.f, 0.f};
  float a[2][8];
#pragma unroll
  for (int r = 0; r < 2; ++r)
#pragma unroll
    for (int j = 0; j < 8; ++j) a[r][j] = 0.f;
#pragma unroll 4
  for (int i = 0; i < 32; ++i) {
    int k = i * 16 + ko;
    float4 kx = kslo[k], ky = kshi[k];
    float4 vx = vslo[k], vy = vshi[k];
#pragma unroll
    for (int r = 0; r < 2; ++r) {
      float s = qa[r].x * kx.x + qa[r].y * kx.y + qa[r].z * kx.z + qa[r].w * kx.w +
                qb[r].x * ky.x + qb[r].y * ky.y + qb[r].z * ky.z + qb[r].w * ky.w;
      float p = exp2f(s);  // |orig s| <= 2.83: no max subtraction needed
      l[r] += p;
      a[r][0] = fmaf(p, vx.x, a[r][0]);
      a[r][1] = fmaf(p, vx.y, a[r][1]);
      a[r][2] = fmaf(p, vx.z, a[r][2]);
      a[r][3] = fmaf(p, vx.w, a[r][3]);
      a[r][4] = fmaf(p, vy.x, a[r][4]);
      a[r][5] = fmaf(p, vy.y, a[r][5]);
      a[r][6] = fmaf(p, vy.z, a[r][6]);
      a[r][7] = fmaf(p, vy.w, a[r][7]);
    }
  }
#pragma unroll
  for (int mm = 1; mm <= 8; mm <<= 1) {  // reduce over 16 k-parts (in-wave)
#pragma unroll
    for (int r = 0; r < 2; ++r) {
      l[r] += __shfl_xor(l[r], mm);
#pragma unroll
      for (int j = 0; j < 8; ++j) a[r][j] += __shfl_xor(a[r][j], mm);
    }
  }
  if (ko == 0) {
    int b = bh >> 4, h = bh & 15;
    float* aout = ws + AOUT_OFF;
#pragma unroll
    for (int r = 0; r < 2; ++r) {
      float inv = 1.f / l[r];
      float* d = aout + ((size_t)(b * 512 + row0 + r)) * 128 + h * 8;
      ((float4*)d)[0] = make_float4(a[r][0] * inv, a[r][1] * inv,
                                    a[r][2] * inv, a[r][3] * inv);
      ((float4*)d)[1] = make_float4(a[r][4] * inv, a[r][5] * inv,
                                    a[r][6] * inv, a[r][7] * inv);
    }
  }
}

// ---------------- k_out: out = aout @ Wo^T -----------------------------------
// 4-row tiles, grid 512 = 2/CU. W fragment prefetch before staging barrier.
__global__ __launch_bounds__(256, 2) void k_out(
    const float* __restrict__ ws, const float* __restrict__ Wo,
    float* __restrict__ out) {
  __shared__ float as_[4][128];    // 2 KB
  __shared__ float th[2][4][128];  // 4 KB
  const int t = threadIdx.x;
  const int tile = blockIdx.x;  // 0..511
  const float* aout = ws + AOUT_OFF;
  const int e = t & 127, half = t >> 7;
  float4 w[16];
  {
    const float4* wr = (const float4*)Wo + (size_t)e * 32 + half * 16;
#pragma unroll
    for (int i = 0; i < 16; ++i) w[i] = wr[i];  // in flight during staging
  }
  if (t < 128)
    ((float4*)&as_[0][0])[t] = ((const float4*)(aout + (size_t)tile * 512))[t];
  __syncthreads();
  const float4* as4 = (const float4*)&as_[0][0];
#pragma unroll
  for (int r = 0; r < 4; ++r) {
    float a = 0.f;
    const float4* ar = as4 + r * 32 + half * 16;
#pragma unroll
    for (int i = 0; i < 16; ++i) {
      float4 av = ar[i];  // LDS broadcast
      a = fmaf(av.x, w[i].x, a);
      a = fmaf(av.y, w[i].y, a);
      a = fmaf(av.z, w[i].z, a);
      a = fmaf(av.w, w[i].w, a);
    }
    th[half][r][e] = a;
  }
  __syncthreads();
  if (t < 128) {
    const int cg = t & 31, rg = t >> 5;
    const float4* th4 = (const float4*)&th[0][0][0];
    float4 p0 = th4[rg * 32 + cg];
    float4 p1 = th4[128 + rg * 32 + cg];
    float4 o = make_float4(p0.x + p1.x, p0.y + p1.y, p0.z + p1.z, p0.w + p1.w);
    ((float4*)(out + (size_t)(tile * 4 + rg) * 128))[cg] = o;
  }
}

extern "C" void kernel_launch(void* const* d_in, const int* in_sizes, int n_in,
                              void* d_out, int out_size, void* d_ws, size_t ws_size,
                              hipStream_t stream) {
  const float* x  = (const float*)d_in[0];
  const float* Wq = (const float*)d_in[1];
  const float* Wk = (const float*)d_in[2];
  const float* Wv = (const float*)d_in[3];
  const float* Wo = (const float*)d_in[4];
  const float* qp = (const float*)d_in[5];
  float* out = (float*)d_out;
  float* ws = (float*)d_ws;

  hipLaunchKernelGGL(k_qkvq, dim3(256, 3), dim3(256), 0, stream,
                     x, Wq, Wk, Wv, qp, ws);
  hipLaunchKernelGGL(k_attn, dim3(16, 64), dim3(256), 0, stream, ws);
  hipLaunchKernelGGL(k_out, dim3(512), dim3(256), 0, stream, ws, Wo, out);
}